// Round 2
// baseline (286.107 us; speedup 1.0000x reference)
//
#include <hip/hip_runtime.h>
#include <math.h>

#define HI 240
#define WI 135
#define NPIX (HI * WI)          // 32400
#define NF 1000
#define NCHUNK 20
#define FCHUNK (NF / NCHUNK)    // 50
#define BLK 256
#define FREC 5                  // float4 per face record
#define TW 8                    // tile width (px)
#define TH 8                    // tile height (px)
#define TX_N 17                 // ceil(135/8)
#define TY_N 30                 // 240/8
#define NTILE (TX_N * TY_N)     // 510
#define TPB 4                   // tiles (waves) per block
#define NBX ((NTILE + TPB - 1) / TPB)   // 128
#define TOTAL_BLOCKS (NBX * NCHUNK)     // 2560

// Face record (5 x float4):
//   r0 = (p0x, p0y, e0x, e0y)   edge 0: v0 -> v1
//   r1 = (p1x, p1y, e1x, e1y)   edge 1: v1 -> v2
//   r2 = (p2x, p2y, e2x, e2y)   edge 2: v2 -> v0
//   r3 = (rden0, rden1, rden2, tz_valid)
//   r4 = (bbox xmin, ymin, xmax, ymax)

__device__ __forceinline__ void project(float x, float y, float z,
                                        float& px, float& py) {
#pragma clang fp contract(off)
    // Bitwise-mirrors ref: z=max(v_z,1e-6); px=(1000*(-x)/z + 512)/1024*W; etc.
    float zc = fmaxf(z, 1e-6f);
    px = ((1000.0f * (-x)) / zc + 512.0f) / 1024.0f * (float)WI;
    py = ((1000.0f * (-y)) / zc + 512.0f) / 1024.0f * (float)HI;
}

__global__ __launch_bounds__(BLK) void prep_kernel(
    const float* __restrict__ verts, const int* __restrict__ faces,
    float* __restrict__ out, float4* __restrict__ frec, int* __restrict__ counter)
{
#pragma clang fp contract(off)
    int tid = blockIdx.x * BLK + threadIdx.x;
    // zero loss slot + sil accumulator (harness poisons d_out with 0xAA)
    if (tid <= NPIX) out[tid] = 0.0f;
    if (tid == 0) *counter = 0;
    if (tid >= NF) return;

    int i0 = faces[3 * tid + 0], i1 = faces[3 * tid + 1], i2 = faces[3 * tid + 2];
    float x0 = verts[3 * i0 + 0], y0 = verts[3 * i0 + 1], z0 = verts[3 * i0 + 2];
    float x1 = verts[3 * i1 + 0], y1 = verts[3 * i1 + 1], z1 = verts[3 * i1 + 2];
    float x2 = verts[3 * i2 + 0], y2 = verts[3 * i2 + 1], z2 = verts[3 * i2 + 2];

    float p0x, p0y, p1x, p1y, p2x, p2y;
    project(x0, y0, z0, p0x, p0y);
    project(x1, y1, z1, p1x, p1y);
    project(x2, y2, z2, p2x, p2y);

    float e0x = p1x - p0x, e0y = p1y - p0y;
    float e1x = p2x - p1x, e1y = p2y - p1y;
    float e2x = p0x - p2x, e2y = p0y - p2y;
    float den0 = (e0x * e0x + e0y * e0y) + 1e-12f;
    float den1 = (e1x * e1x + e1y * e1y) + 1e-12f;
    float den2 = (e2x * e2x + e2y * e2y) + 1e-12f;

    float tz = ((z0 + z1) + z2) / 3.0f;
    bool tzok = tz > 1e-6f;

    // Pathology rule (provable): an fp cross-product sign flip outside
    // bbox+0.3px requires TWO simultaneously-ambiguous crosses; with
    // relative cross rounding ~1.2e-7 and wedge suppression sin(theta) >=
    // area2/lmax^2, the face is safe iff area2 >= 4e-3*lmax^2 and
    // lmax <= 2000px. Unsafe (sliver/dup/huge) faces get an infinite bbox
    // and are evaluated everywhere with bitwise-matching cross arithmetic.
    float area2 = fabsf(e0x * e1y - e0y * e1x);
    float l2max = fmaxf(den0, fmaxf(den1, den2));
    bool dup = (i0 == i1) || (i1 == i2) || (i2 == i0);
    bool patho = dup || (area2 < 4.0e-3f * l2max) || (l2max > 4.0e6f);

    float bx0, by0, bx1, by1;
    if (!tzok) {               // contribution exactly zero everywhere
        bx0 = 1e30f; by0 = 1e30f; bx1 = -1e30f; by1 = -1e30f;
    } else if (patho) {        // always evaluate
        bx0 = -1e30f; by0 = -1e30f; bx1 = 1e30f; by1 = 1e30f;
    } else {
        // margin 0.3 px >= sqrt(BLUR)=0.0304 blur band + fp ambiguity band
        bx0 = fminf(p0x, fminf(p1x, p2x)) - 0.3f;
        by0 = fminf(p0y, fminf(p1y, p2y)) - 0.3f;
        bx1 = fmaxf(p0x, fmaxf(p1x, p2x)) + 0.3f;
        by1 = fmaxf(p0y, fmaxf(p1y, p2y)) + 0.3f;
    }

    frec[FREC * tid + 0] = make_float4(p0x, p0y, e0x, e0y);
    frec[FREC * tid + 1] = make_float4(p1x, p1y, e1x, e1y);
    frec[FREC * tid + 2] = make_float4(p2x, p2y, e2x, e2y);
    frec[FREC * tid + 3] = make_float4(1.0f / den0, 1.0f / den1, 1.0f / den2,
                                       tzok ? 1.0f : 0.0f);
    frec[FREC * tid + 4] = make_float4(bx0, by0, bx1, by1);
}

__global__ __launch_bounds__(BLK) void sil_kernel(
    const float4* __restrict__ frec, const float* __restrict__ gt,
    float* __restrict__ out, int* __restrict__ counter)
{
    __shared__ float4 sf[FCHUNK * FREC];   // 4000 B
    __shared__ int lastflag;
    __shared__ float wsum[BLK / 64];

    const float4* src = frec + (size_t)blockIdx.y * (FCHUNK * FREC);
    for (int i = threadIdx.x; i < FCHUNK * FREC; i += BLK) sf[i] = src[i];
    __syncthreads();

    int wave = threadIdx.x >> 6, lane = threadIdx.x & 63;
    int tile = blockIdx.x * TPB + wave;

    if (tile < NTILE) {
        int ty = tile / TX_N, tx = tile - ty * TX_N;
        int col = tx * TW + (lane & 7);
        int row = ty * TH + (lane >> 3);
        bool live = col < WI;                  // x-tail tiles partially valid
        int q = row * WI + col;
        float px = (float)col + 0.5f;
        float py = (float)row + 0.5f;
        // wave-uniform 8x8 tile rect
        float wx0 = (float)(tx * TW) + 0.5f, wx1 = (float)(tx * TW + TW - 1) + 0.5f;
        float wy0 = (float)(ty * TH) + 0.5f, wy1 = (float)(ty * TH + TH - 1) + 0.5f;

        float sum = 0.0f;
        for (int f = 0; f < FCHUNK; ++f) {
            float4 bb = sf[FREC * f + 4];
            // wave-uniform reject: skipped faces contribute exactly 0
            if (bb.x > wx1 || bb.z < wx0 || bb.y > wy1 || bb.w < wy0) continue;

            float4 r0v = sf[FREC * f + 0];
            float4 r1v = sf[FREC * f + 1];
            float4 r2v = sf[FREC * f + 2];
            float4 dv  = sf[FREC * f + 3];

            float a0x = px - r0v.x, a0y = py - r0v.y;
            float a1x = px - r1v.x, a1y = py - r1v.y;
            float a2x = px - r2v.x, a2y = py - r2v.y;

            float c0, c1, c2;
            {
#pragma clang fp contract(off)
                // bitwise-match ref (sign-test cliff)
                c0 = r0v.z * a0y - r0v.w * a0x;
                c1 = r1v.z * a1y - r1v.w * a1x;
                c2 = r2v.z * a2y - r2v.w * a2x;
            }
            bool pos = (c0 >= 0.0f) & (c1 >= 0.0f) & (c2 >= 0.0f);
            bool neg = (c0 <= 0.0f) & (c1 <= 0.0f) & (c2 <= 0.0f);

            // smooth region: FMA + reciprocal are fine (2e-2 slack)
            float t0 = fminf(fmaxf((a0x * r0v.z + a0y * r0v.w) * dv.x, 0.0f), 1.0f);
            float t1 = fminf(fmaxf((a1x * r1v.z + a1y * r1v.w) * dv.y, 0.0f), 1.0f);
            float t2 = fminf(fmaxf((a2x * r2v.z + a2y * r2v.w) * dv.z, 0.0f), 1.0f);
            float u0x = a0x - t0 * r0v.z, u0y = a0y - t0 * r0v.w;
            float u1x = a1x - t1 * r1v.z, u1y = a1y - t1 * r1v.w;
            float u2x = a2x - t2 * r2v.z, u2y = a2y - t2 * r2v.w;
            float d20 = u0x * u0x + u0y * u0y;
            float d21 = u1x * u1x + u1y * u1y;
            float d22 = u2x * u2x + u2y * u2y;
            float d2m = fminf(d20, fminf(d21, d22));

            bool inside = pos | neg;
            // contribution = log1p(-sigmoid(-sd/SIGMA)) = -softplus(u),
            // u = -sd/SIGMA  (inside: +d2m/SIGMA, outside: -d2m/SIGMA)
            float uu = (inside ? d2m : -d2m) * 1.0e4f;
            bool valid = (dv.w != 0.0f) & (inside | (d2m <= 9.2102404e-4f));
            float sp = fmaxf(uu, 0.0f) + __logf(1.0f + __expf(-fabsf(uu)));
            sum -= valid ? sp : 0.0f;
        }
        if (live && sum != 0.0f) atomicAdd(&out[1 + q], sum);
    }

    // ---- last-block finalization (fused fin kernel) ----
    __threadfence();
    if (threadIdx.x == 0) {
        int old = __hip_atomic_fetch_add(counter, 1, __ATOMIC_ACQ_REL,
                                         __HIP_MEMORY_SCOPE_AGENT);
        lastflag = (old == TOTAL_BLOCKS - 1) ? 1 : 0;
    }
    __syncthreads();
    if (lastflag) {
        float c = 0.0f;
        for (int p = threadIdx.x; p < NPIX; p += BLK) {
            float s = __hip_atomic_load(&out[1 + p], __ATOMIC_RELAXED,
                                        __HIP_MEMORY_SCOPE_AGENT);
            float alpha = 1.0f - expf(s);      // exp of big-negative -> 0 -> alpha=1
            out[1 + p] = alpha;
            c += fabsf(alpha - gt[p]);
        }
        for (int off = 32; off > 0; off >>= 1) c += __shfl_down(c, off, 64);
        if ((threadIdx.x & 63) == 0) wsum[threadIdx.x >> 6] = c;
        __syncthreads();
        if (threadIdx.x == 0) {
            float s = 0.0f;
            for (int w = 0; w < BLK / 64; ++w) s += wsum[w];
            out[0] = s * (1.0f / (float)NPIX);
        }
    }
}

extern "C" void kernel_launch(void* const* d_in, const int* in_sizes, int n_in,
                              void* d_out, int out_size, void* d_ws, size_t ws_size,
                              hipStream_t stream)
{
    const float* verts = (const float*)d_in[0];
    const float* gt    = (const float*)d_in[1];
    const int*   faces = (const int*)d_in[2];
    float* out = (float*)d_out;          // out[0]=loss, out[1..]=sil (H*W)
    float4* frec = (float4*)d_ws;        // 1000 * 5 * 16 B = 80 KB scratch
    int* counter = (int*)((char*)d_ws + NF * FREC * sizeof(float4));

    int pgrid = (NPIX + 1 + BLK - 1) / BLK;   // 127 (covers zeroing + 1000 faces)
    prep_kernel<<<pgrid, BLK, 0, stream>>>(verts, faces, out, frec, counter);

    dim3 sgrid(NBX, NCHUNK);                  // 128 x 20 = 2560 blocks
    sil_kernel<<<sgrid, BLK, 0, stream>>>(frec, gt, out, counter);
}

// Round 3
// 97.566 us; speedup vs baseline: 2.9325x; 2.9325x over previous
//
#include <hip/hip_runtime.h>
#include <math.h>

#define HI 240
#define WI 135
#define NPIX (HI * WI)          // 32400
#define NF 1000
#define NCHUNK 20
#define FCHUNK (NF / NCHUNK)    // 50
#define BLK 256
#define FREC 5                  // float4 per face record
#define TW 8                    // tile width (px)
#define TH 8                    // tile height (px)
#define TX_N 17                 // ceil(135/8)
#define TY_N 30                 // 240/8
#define NTILE (TX_N * TY_N)     // 510
#define TPB 4                   // tiles (waves) per block
#define NBX ((NTILE + TPB - 1) / TPB)   // 128

// Face record (5 x float4):
//   r0 = (p0x, p0y, e0x, e0y)   edge 0: v0 -> v1
//   r1 = (p1x, p1y, e1x, e1y)   edge 1: v1 -> v2
//   r2 = (p2x, p2y, e2x, e2y)   edge 2: v2 -> v0
//   r3 = (rden0, rden1, rden2, tz_valid)
//   r4 = (bbox xmin, ymin, xmax, ymax)

__device__ __forceinline__ void project(float x, float y, float z,
                                        float& px, float& py) {
#pragma clang fp contract(off)
    // Bitwise-mirrors ref: z=max(v_z,1e-6); px=(1000*(-x)/z + 512)/1024*W; etc.
    float zc = fmaxf(z, 1e-6f);
    px = ((1000.0f * (-x)) / zc + 512.0f) / 1024.0f * (float)WI;
    py = ((1000.0f * (-y)) / zc + 512.0f) / 1024.0f * (float)HI;
}

__global__ __launch_bounds__(BLK) void prep_kernel(
    const float* __restrict__ verts, const int* __restrict__ faces,
    float* __restrict__ out, float4* __restrict__ frec)
{
#pragma clang fp contract(off)
    int tid = blockIdx.x * BLK + threadIdx.x;
    // zero loss slot + sil accumulator (harness poisons d_out with 0xAA)
    if (tid <= NPIX) out[tid] = 0.0f;
    if (tid >= NF) return;

    int i0 = faces[3 * tid + 0], i1 = faces[3 * tid + 1], i2 = faces[3 * tid + 2];
    float x0 = verts[3 * i0 + 0], y0 = verts[3 * i0 + 1], z0 = verts[3 * i0 + 2];
    float x1 = verts[3 * i1 + 0], y1 = verts[3 * i1 + 1], z1 = verts[3 * i1 + 2];
    float x2 = verts[3 * i2 + 0], y2 = verts[3 * i2 + 1], z2 = verts[3 * i2 + 2];

    float p0x, p0y, p1x, p1y, p2x, p2y;
    project(x0, y0, z0, p0x, p0y);
    project(x1, y1, z1, p1x, p1y);
    project(x2, y2, z2, p2x, p2y);

    float e0x = p1x - p0x, e0y = p1y - p0y;
    float e1x = p2x - p1x, e1y = p2y - p1y;
    float e2x = p0x - p2x, e2y = p0y - p2y;
    float den0 = (e0x * e0x + e0y * e0y) + 1e-12f;
    float den1 = (e1x * e1x + e1y * e1y) + 1e-12f;
    float den2 = (e2x * e2x + e2y * e2y) + 1e-12f;

    float tz = ((z0 + z1) + z2) / 3.0f;
    bool tzok = tz > 1e-6f;

    // Pathology rule (provable): an fp cross-product sign flip outside
    // bbox+0.3px requires TWO simultaneously-ambiguous crosses; with
    // relative cross rounding ~1.2e-7 and wedge suppression sin(theta) >=
    // area2/lmax^2, the face is safe iff area2 >= 4e-3*lmax^2 and
    // lmax <= 2000px. Unsafe (sliver/dup/huge) faces get an infinite bbox
    // and are evaluated everywhere with bitwise-matching cross arithmetic.
    float area2 = fabsf(e0x * e1y - e0y * e1x);
    float l2max = fmaxf(den0, fmaxf(den1, den2));
    bool dup = (i0 == i1) || (i1 == i2) || (i2 == i0);
    bool patho = dup || (area2 < 4.0e-3f * l2max) || (l2max > 4.0e6f);

    float bx0, by0, bx1, by1;
    if (!tzok) {               // contribution exactly zero everywhere
        bx0 = 1e30f; by0 = 1e30f; bx1 = -1e30f; by1 = -1e30f;
    } else if (patho) {        // always evaluate
        bx0 = -1e30f; by0 = -1e30f; bx1 = 1e30f; by1 = 1e30f;
    } else {
        // margin 0.3 px >= sqrt(BLUR)=0.0304 blur band + fp ambiguity band
        bx0 = fminf(p0x, fminf(p1x, p2x)) - 0.3f;
        by0 = fminf(p0y, fminf(p1y, p2y)) - 0.3f;
        bx1 = fmaxf(p0x, fmaxf(p1x, p2x)) + 0.3f;
        by1 = fmaxf(p0y, fmaxf(p1y, p2y)) + 0.3f;
    }

    frec[FREC * tid + 0] = make_float4(p0x, p0y, e0x, e0y);
    frec[FREC * tid + 1] = make_float4(p1x, p1y, e1x, e1y);
    frec[FREC * tid + 2] = make_float4(p2x, p2y, e2x, e2y);
    frec[FREC * tid + 3] = make_float4(1.0f / den0, 1.0f / den1, 1.0f / den2,
                                       tzok ? 1.0f : 0.0f);
    frec[FREC * tid + 4] = make_float4(bx0, by0, bx1, by1);
}

// NOTE (R2 post-mortem): NO device-scope fences / atomic handshakes in here.
// The fused last-block finalization (__threadfence + ACQ_REL agent atomic per
// block) cost ~220us in fence traffic on non-coherent per-XCD L2s. Kernel
// boundaries provide device-wide visibility for free.
__global__ __launch_bounds__(BLK) void sil_kernel(
    const float4* __restrict__ frec, float* __restrict__ out)
{
    __shared__ float4 sf[FCHUNK * FREC];   // 4000 B

    const float4* src = frec + (size_t)blockIdx.y * (FCHUNK * FREC);
    for (int i = threadIdx.x; i < FCHUNK * FREC; i += BLK) sf[i] = src[i];
    __syncthreads();

    int wave = threadIdx.x >> 6, lane = threadIdx.x & 63;
    int tile = blockIdx.x * TPB + wave;
    if (tile >= NTILE) return;

    int ty = tile / TX_N, tx = tile - ty * TX_N;
    int col = tx * TW + (lane & 7);
    int row = ty * TH + (lane >> 3);
    bool live = col < WI;                  // x-tail tiles partially valid
    int q = row * WI + col;
    float px = (float)col + 0.5f;
    float py = (float)row + 0.5f;
    // wave-uniform 8x8 tile rect
    float wx0 = (float)(tx * TW) + 0.5f, wx1 = (float)(tx * TW + TW - 1) + 0.5f;
    float wy0 = (float)(ty * TH) + 0.5f, wy1 = (float)(ty * TH + TH - 1) + 0.5f;

    float sum = 0.0f;
    for (int f = 0; f < FCHUNK; ++f) {
        float4 bb = sf[FREC * f + 4];
        // wave-uniform reject: skipped faces contribute exactly 0
        if (bb.x > wx1 || bb.z < wx0 || bb.y > wy1 || bb.w < wy0) continue;

        float4 r0v = sf[FREC * f + 0];
        float4 r1v = sf[FREC * f + 1];
        float4 r2v = sf[FREC * f + 2];
        float4 dv  = sf[FREC * f + 3];

        float a0x = px - r0v.x, a0y = py - r0v.y;
        float a1x = px - r1v.x, a1y = py - r1v.y;
        float a2x = px - r2v.x, a2y = py - r2v.y;

        float c0, c1, c2;
        {
#pragma clang fp contract(off)
            // bitwise-match ref (sign-test cliff)
            c0 = r0v.z * a0y - r0v.w * a0x;
            c1 = r1v.z * a1y - r1v.w * a1x;
            c2 = r2v.z * a2y - r2v.w * a2x;
        }
        bool pos = (c0 >= 0.0f) & (c1 >= 0.0f) & (c2 >= 0.0f);
        bool neg = (c0 <= 0.0f) & (c1 <= 0.0f) & (c2 <= 0.0f);

        // smooth region: FMA + reciprocal are fine (2e-2 slack)
        float t0 = fminf(fmaxf((a0x * r0v.z + a0y * r0v.w) * dv.x, 0.0f), 1.0f);
        float t1 = fminf(fmaxf((a1x * r1v.z + a1y * r1v.w) * dv.y, 0.0f), 1.0f);
        float t2 = fminf(fmaxf((a2x * r2v.z + a2y * r2v.w) * dv.z, 0.0f), 1.0f);
        float u0x = a0x - t0 * r0v.z, u0y = a0y - t0 * r0v.w;
        float u1x = a1x - t1 * r1v.z, u1y = a1y - t1 * r1v.w;
        float u2x = a2x - t2 * r2v.z, u2y = a2y - t2 * r2v.w;
        float d20 = u0x * u0x + u0y * u0y;
        float d21 = u1x * u1x + u1y * u1y;
        float d22 = u2x * u2x + u2y * u2y;
        float d2m = fminf(d20, fminf(d21, d22));

        bool inside = pos | neg;
        // contribution = log1p(-sigmoid(-sd/SIGMA)) = -softplus(u),
        // u = -sd/SIGMA  (inside: +d2m/SIGMA, outside: -d2m/SIGMA)
        float uu = (inside ? d2m : -d2m) * 1.0e4f;
        bool valid = (dv.w != 0.0f) & (inside | (d2m <= 9.2102404e-4f));
        float sp = fmaxf(uu, 0.0f) + __logf(1.0f + __expf(-fabsf(uu)));
        sum -= valid ? sp : 0.0f;
    }
    // plain fp atomic, no fence; fin kernel launch provides visibility
    if (live && sum != 0.0f) atomicAdd(&out[1 + q], sum);
}

__global__ __launch_bounds__(BLK) void fin_kernel(
    const float* __restrict__ gt, float* __restrict__ out)
{
    __shared__ float wsum[BLK / 64];
    int q = blockIdx.x * BLK + threadIdx.x;
    float c = 0.0f;
    if (q < NPIX) {
        float alpha = 1.0f - expf(out[1 + q]);   // exp(big negative) -> 0 -> alpha=1
        out[1 + q] = alpha;
        c = fabsf(alpha - gt[q]);
    }
    for (int off = 32; off > 0; off >>= 1) c += __shfl_down(c, off, 64);
    if ((threadIdx.x & 63) == 0) wsum[threadIdx.x >> 6] = c;
    __syncthreads();
    if (threadIdx.x == 0) {
        float s = 0.0f;
        for (int w = 0; w < BLK / 64; ++w) s += wsum[w];
        atomicAdd(&out[0], s * (1.0f / (float)NPIX));
    }
}

extern "C" void kernel_launch(void* const* d_in, const int* in_sizes, int n_in,
                              void* d_out, int out_size, void* d_ws, size_t ws_size,
                              hipStream_t stream)
{
    const float* verts = (const float*)d_in[0];
    const float* gt    = (const float*)d_in[1];
    const int*   faces = (const int*)d_in[2];
    float* out = (float*)d_out;          // out[0]=loss, out[1..]=sil (H*W)
    float4* frec = (float4*)d_ws;        // 1000 * 5 * 16 B = 80 KB scratch

    int pgrid = (NPIX + 1 + BLK - 1) / BLK;   // 127 (covers zeroing + 1000 faces)
    prep_kernel<<<pgrid, BLK, 0, stream>>>(verts, faces, out, frec);

    dim3 sgrid(NBX, NCHUNK);                  // 128 x 20 = 2560 blocks
    sil_kernel<<<sgrid, BLK, 0, stream>>>(frec, out);

    fin_kernel<<<(NPIX + BLK - 1) / BLK, BLK, 0, stream>>>(gt, out);
}